// Round 7
// baseline (997.781 us; speedup 1.0000x reference)
//
#include <hip/hip_runtime.h>

#define NN 10000
#define EE 100000
#define GG 64
#define EPSV 1e-5f
#define NBLK 625           // 625*16 = 10000 nodes; must be <= 3 blocks/CU * 256 CU = 768 resident
#define NPB 16             // nodes per block (2 tiles of 8)
#define SLOTS 1056         // 32*32 P-slots + 32 bias slots (w2r layout [i][slot])
#define PST 36             // P2 c-stride per o-row (c=0..31 data, 32 bias, 33..35 pad)
#define PNODE (32*PST)     // 1152 floats per node in LDS
#define HBLK 391           // ceil(EE/256) edge-parallel window
#define WBLK 160           // w2t window: 5 blocks per i, i=0..31

// workspace offsets (bytes, 16B-aligned)
#define OFF_W2R1   0
#define OFF_W2R2   135168
#define OFF_MSG1   270336       // 12,800,000
#define OFF_MSG2   13070336     // 12,800,000
#define OFF_EACSR  25870336     // 1,600,000
#define OFF_CNT    27470336     // 40,000
#define OFF_DEG    27510336     // 40,000
#define OFF_PSUM   27550336     // 8,192
#define OFF_ROWPTR 27558528     // 40,064
#define OFF_CURSOR 27598592     // 40,000
#define OFF_COLPTR 27638592     // 40,064
#define OFF_CCUR   27678656     // 40,000
#define OFF_MSRC   27718656     // 400,000
#define OFF_CPOS   28118656     // 400,000
#define OFF_BARS   28518656     // 64 (7 slots used; memset-zeroed each launch)

// Manual grid barrier: release fence (buffer_wbl2) -> device-scope atomic arrive ->
// agent-scope spin -> acquire fence (inv). Round-based target survives rocprof replay.
// Requires all NBLK blocks resident: LDS=40,960B (4/CU) + launch_bounds(256,3) (VGPR<=168)
// guarantee >=3 blocks/CU -> capacity 768 >= 625.
__device__ __forceinline__ void gsync(int* bars, int slot) {
    __syncthreads();                       // block's stores drained (vmcnt 0 at barrier)
    if (threadIdx.x == 0) {
        __threadfence();                   // release: write back this XCD's L2
        int base = atomicAdd(&bars[slot], 1);
        int target = (base / NBLK + 1) * NBLK;
        while (__hip_atomic_load(&bars[slot], __ATOMIC_RELAXED,
                                 __HIP_MEMORY_SCOPE_AGENT) < target)
            __builtin_amdgcn_s_sleep(2);
        __threadfence();                   // acquire: invalidate stale L1/L2 lines
    }
    __syncthreads();
}

__global__ __launch_bounds__(256, 3) void k_mega(
    const float* __restrict__ x, const float* __restrict__ eattr,
    const float* __restrict__ e1w1, const float* __restrict__ e1b1,
    const float* __restrict__ e2w1, const float* __restrict__ e2b1,
    const float* __restrict__ e1w2, const float* __restrict__ e1b2,
    const float* __restrict__ e2w2, const float* __restrict__ e2b2,
    const float* __restrict__ root1, const float* __restrict__ bias1,
    const float* __restrict__ root2, const float* __restrict__ bias2,
    const float* __restrict__ bn1g, const float* __restrict__ bn1b,
    const float* __restrict__ bn1m, const float* __restrict__ bn1v,
    const float* __restrict__ bn2g, const float* __restrict__ bn2b,
    const float* __restrict__ bn2m, const float* __restrict__ bn2v,
    const float* __restrict__ r1w, const float* __restrict__ r1b,
    const float* __restrict__ r2w, const float* __restrict__ r2b,
    const int* __restrict__ ei, const int* __restrict__ batch,
    float* __restrict__ out, char* __restrict__ ws)
{
    __shared__ float xs[8][32];          // 1,024 B (scan scratch: 256 ints)
    __shared__ float P2[8 * PNODE];      // 36,864 B (combine: gb scratch; readout scratch)
    __shared__ float shx[8][32];         // 1,024 B (Phase-B h transpose; combine2 vals)
    __shared__ float xmid_s[NPB][32];    // 2,048 B  -> total 40,960 B exactly (4 blocks/CU)

    float*  w2r1   = (float*) (ws + OFF_W2R1);
    float*  w2r2   = (float*) (ws + OFF_W2R2);
    float*  msg1   = (float*) (ws + OFF_MSG1);
    float*  msg2   = (float*) (ws + OFF_MSG2);
    float4* ea_csr = (float4*)(ws + OFF_EACSR);
    int*    cnt    = (int*)   (ws + OFF_CNT);
    int*    deg    = (int*)   (ws + OFF_DEG);
    float*  psum   = (float*) (ws + OFF_PSUM);
    int*    rowptr = (int*)   (ws + OFF_ROWPTR);
    int*    cursor = (int*)   (ws + OFF_CURSOR);
    int*    colptr = (int*)   (ws + OFF_COLPTR);
    int*    ccursor= (int*)   (ws + OFF_CCUR);
    int*    msrc   = (int*)   (ws + OFF_MSRC);
    int*    cpos   = (int*)   (ws + OFF_CPOS);
    int*    bars   = (int*)   (ws + OFF_BARS);

    int bid  = blockIdx.x;
    int t    = threadIdx.x;
    int gtid = bid * 256 + t;
    int o    = t & 31;
    int grp  = t >> 5;

    // ---- phase 0: zero cnt/deg/psum + weight transposes ----
    if (gtid < NN) { cnt[gtid] = 0; deg[gtid] = 0; }
    if (gtid < GG * 32) psum[gtid] = 0.f;
    if (bid >= HBLK && bid < HBLK + WBLK) {
        int b2i = bid - HBLK;
        int s = (b2i % 5) * 256 + t;
        int i = b2i / 5;
        if (s < SLOTS) {
            float va = (s < 1024) ? e1w2[(s >> 5) * 1024 + i * 32 + (s & 31)]
                                  : e1b2[i * 32 + (s - 1024)];
            float vb = (s < 1024) ? e2w2[(s >> 5) * 1024 + i * 32 + (s & 31)]
                                  : e2b2[i * 32 + (s - 1024)];
            w2r1[i * SLOTS + s] = va;
            w2r2[i * SLOTS + s] = vb;
        }
    }
    gsync(bars, 0);

    // ---- phase 1: degree histograms ----
    if (gtid < EE) {
        atomicAdd(&cnt[ei[EE + gtid]], 1);               // dst in-degree
        atomicAdd(&deg[ei[gtid]], 1);                    // src out-degree
    }
    gsync(bars, 1);

    // ---- phase 2: scans (block 0: CSR from deg; block 1: CSC from cnt) ----
    if (bid < 2) {
        const int* srcv = bid ? cnt : deg;
        int* dp = bid ? colptr : rowptr;
        int* dc = bid ? ccursor : cursor;
        int* buf = (int*)xs;                             // 256 ints
        int vloc[40];
        int ssum = 0;
        int base = t * 40;
        #pragma unroll
        for (int k = 0; k < 40; k++) {
            int idx = base + k;
            vloc[k] = (idx < NN) ? srcv[idx] : 0;
            ssum += vloc[k];
        }
        buf[t] = ssum;
        for (int off = 1; off < 256; off <<= 1) {
            __syncthreads();
            int val = buf[t] + ((t >= off) ? buf[t - off] : 0);
            __syncthreads();
            buf[t] = val;
        }
        __syncthreads();
        int carry = (t > 0) ? buf[t - 1] : 0;
        #pragma unroll
        for (int k = 0; k < 40; k++) {
            int idx = base + k;
            if (idx < NN) { dp[idx] = carry; dc[idx] = carry; }
            carry += vloc[k];
        }
        if (t == 255) dp[NN] = buf[255];
    }
    gsync(bars, 2);

    // ---- phase 3: scatter (CSR slots + ea_csr + msrc + CSC pos list) ----
    if (gtid < EE) {
        int sn = ei[gtid];
        int dn = ei[EE + gtid];
        float4 a = *(const float4*)&eattr[(size_t)gtid * 4];
        int pos = atomicAdd(&cursor[sn], 1);
        msrc[pos] = sn;
        ea_csr[pos] = a;
        int cp = atomicAdd(&ccursor[dn], 1);
        cpos[cp] = pos;
    }
    gsync(bars, 3);

    // ---- layers ----
    for (int layer = 0; layer < 2; ++layer) {
        const float* w2r  = layer ? w2r2 : w2r1;
        const float* w1   = layer ? e2w1 : e1w1;
        const float* b1   = layer ? e2b1 : e1b1;
        float*       msgL = layer ? msg2 : msg1;
        const float* root = layer ? root2 : root1;
        const float* bias = layer ? bias2 : bias1;
        const float* bg   = layer ? bn2g : bn1g;
        const float* bbn  = layer ? bn2b : bn1b;
        const float* bm   = layer ? bn2m : bn1m;
        const float* bv   = layer ? bn2v : bn1v;

        float wc0 = w1[o], wc1 = w1[32 + o], wc2 = w1[64 + o], wc3 = w1[96 + o];
        float hbb = b1[o];
        int cb = 4 * grp;

        for (int tile = 0; tile < 2; ++tile) {
            int n0 = bid * NPB + tile * 8;
            int ebase = rowptr[n0];
            int eend  = rowptr[n0 + 8];

            int pos = ebase + grp;
            float4 aC = make_float4(0.f, 0.f, 0.f, 0.f);
            int srcC = n0;
            if (pos < eend) { aC = ea_csr[pos]; srcC = msrc[pos]; }

            if (layer == 0) xs[grp][o] = x[n0 * 32 + t];
            else            xs[grp][o] = xmid_s[tile * 8 + grp][o];
            __syncthreads();   // xs ready; also orders P2 reuse vs previous tile's Phase B

            // ---- Phase A: P2[n][o][c] = sum_i xs[n][i] * w2r[i][c*32+o] ----
            {
                float acc[4][8];
                #pragma unroll
                for (int k = 0; k < 4; k++)
                    #pragma unroll
                    for (int n = 0; n < 8; n++) acc[k][n] = 0.f;
                #pragma unroll
                for (int j = 0; j < 8; j++) {
                    float wk[4][4];
                    #pragma unroll
                    for (int r = 0; r < 4; r++)
                        #pragma unroll
                        for (int k = 0; k < 4; k++)
                            wk[r][k] = w2r[(4 * j + r) * SLOTS + (cb + k) * 32 + o];
                    #pragma unroll
                    for (int n = 0; n < 8; n++) {
                        float4 xq = *(const float4*)&xs[n][4 * j];
                        #pragma unroll
                        for (int k = 0; k < 4; k++)
                            acc[k][n] += xq.x * wk[0][k] + xq.y * wk[1][k]
                                       + xq.z * wk[2][k] + xq.w * wk[3][k];
                    }
                }
                #pragma unroll
                for (int n = 0; n < 8; n++) {
                    float4 st = make_float4(acc[0][n], acc[1][n], acc[2][n], acc[3][n]);
                    *(float4*)&P2[n * PNODE + o * PST + cb] = st;
                }
            }
            if (t < 32) {
                float wb[32];
                #pragma unroll
                for (int i = 0; i < 32; i++) wb[i] = w2r[i * SLOTS + 1024 + t];
                #pragma unroll
                for (int n = 0; n < 8; n++) {
                    float b = 0.f;
                    #pragma unroll
                    for (int j = 0; j < 8; j++) {
                        float4 xq = *(const float4*)&xs[n][4 * j];
                        b += xq.x * wb[4 * j] + xq.y * wb[4 * j + 1]
                           + xq.z * wb[4 * j + 2] + xq.w * wb[4 * j + 3];
                    }
                    *(float4*)&P2[n * PNODE + t * PST + 32] = make_float4(b, 0.f, 0.f, 0.f);
                }
            }
            __syncthreads();

            // ---- Phase B: 32-lane group per edge; on-the-fly h + in-wave LDS transpose ----
            while (pos < eend) {
                int pn = pos + 8;
                float4 aN = aC; int srcN = srcC;
                if (pn < eend) { aN = ea_csr[pn]; srcN = msrc[pn]; }
                float h = fmaxf(aC.x * wc0 + aC.y * wc1 + aC.z * wc2 + aC.w * wc3 + hbb, 0.f);
                shx[grp][o] = h;
                asm volatile("" ::: "memory");   // write before reads (in-order DS per wave)
                const float* Pn = &P2[(srcC - n0) * PNODE + o * PST];
                float m = Pn[32];                // bias slot
                #pragma unroll
                for (int b = 0; b < 8; b++) {
                    float4 hx = *(const float4*)&shx[grp][4 * b];   // broadcast
                    float4 pq = *(const float4*)&Pn[4 * b];
                    m += hx.x * pq.x + hx.y * pq.y + hx.z * pq.z + hx.w * pq.w;
                }
                msgL[(size_t)pos * 32 + o] = m;  // coalesced 128B store per group
                asm volatile("" ::: "memory");
                pos = pn; aC = aN; srcC = srcN;
            }
        }
        gsync(bars, 4 + layer);                          // msgL complete grid-wide

        // ---- combine: CSC gather + root + BN + ReLU ----
        for (int r = 0; r < 2; ++r) {
            __syncthreads();                             // xs/shx reuse across rounds
            int n0c = bid * NPB + r * 8;
            if (layer == 0) xs[grp][o] = x[n0c * 32 + t];
            else            xs[grp][o] = xmid_s[r * 8 + grp][o];
            __syncthreads();
            int k = grp, n = n0c + k;
            float rt = bias[o];
            #pragma unroll
            for (int i = 0; i < 32; i++) rt += xs[k][i] * root[i * 32 + o];
            int jbase = colptr[n], jend = colptr[n + 1];
            float acc = 0.f;
            for (int jb = jbase; jb < jend; jb += 32) {
                int nrem = jend - jb;
                int lim = (nrem < 32) ? nrem : 32;
                int cv = 0;
                if (o < lim) cv = cpos[jb + o];
                for (int j = 0; j < lim; j += 8) {
                    float v[8];
                    #pragma unroll
                    for (int q = 0; q < 8; q++) {
                        if (j + q < lim) {
                            int cj = __shfl(cv, j + q, 32);
                            v[q] = msgL[(size_t)cj * 32 + o];
                        } else v[q] = 0.f;
                    }
                    #pragma unroll
                    for (int q = 0; q < 8; q++) acc += v[q];
                }
            }
            float a = acc / fmaxf((float)(jend - jbase), 1.f);
            float val = a + rt;
            val = (val - bm[o]) * rsqrtf(bv[o] + EPSV) * bg[o] + bbn[o];
            val = fmaxf(val, 0.f);
            if (layer == 0) {
                xmid_s[r * 8 + k][o] = val;              // block-local; same-thread reuse
            } else {
                int* gbp = (int*)P2;                     // P2 idle during combine
                shx[k][o] = val;
                if (o == 0) gbp[k] = batch[n];
                __syncthreads();
                if (k == 0) {
                    float pacc = shx[0][o];
                    int g = gbp[0];
                    #pragma unroll
                    for (int k2 = 1; k2 < 8; k2++) {
                        if (gbp[k2] == g) pacc += shx[k2][o];
                        else {
                            atomicAdd(&psum[(size_t)g * 32 + o], pacc);
                            g = gbp[k2]; pacc = shx[k2][o];
                        }
                    }
                    atomicAdd(&psum[(size_t)g * 32 + o], pacc);
                }
            }
        }
        if (layer == 1) gsync(bars, 6);                  // psum ready
    }

    // ---- readout (block 0 only; P2 reused as scratch) ----
    if (bid == 0) {
        __syncthreads();
        float* w1s = P2;            // 512
        float* b1s = P2 + 512;      // 16
        float* w2s = P2 + 528;      // 16
        float* ps  = P2 + 544;      // 2048
        int cnt_g = 0;
        if (t < GG) {
            int lo = 0, hi = NN;
            while (lo < hi) { int m2 = (lo + hi) >> 1; if (batch[m2] < t) lo = m2 + 1; else hi = m2; }
            int lb = lo;
            lo = 0; hi = NN;
            while (lo < hi) { int m2 = (lo + hi) >> 1; if (batch[m2] < t + 1) lo = m2 + 1; else hi = m2; }
            cnt_g = lo - lb;
        }
        w1s[t] = r1w[t];
        w1s[t + 256] = r1w[t + 256];
        if (t < 16) { b1s[t] = r1b[t]; w2s[t] = r2w[t]; }
        #pragma unroll
        for (int i = 0; i < GG * 32 / 256; i++) ps[t + i * 256] = psum[t + i * 256];
        __syncthreads();
        if (t < GG) {
            float inv = 1.f / fmaxf((float)cnt_g, 1.f);
            float acc2 = r2b[0];
            #pragma unroll
            for (int j = 0; j < 16; j++) {
                float dot = 0.f;
                #pragma unroll
                for (int c = 0; c < 32; c++) dot += ps[t * 32 + c] * w1s[c * 16 + j];
                float z = dot * inv + b1s[j];
                acc2 += fmaxf(z, 0.f) * w2s[j];
            }
            out[t] = acc2;
        }
    }
}

extern "C" void kernel_launch(void* const* d_in, const int* in_sizes, int n_in,
                              void* d_out, int out_size, void* d_ws, size_t ws_size,
                              hipStream_t stream) {
    const float* x       = (const float*)d_in[0];
    const float* eattr   = (const float*)d_in[1];
    const float* e1_w1   = (const float*)d_in[2];
    const float* e1_b1   = (const float*)d_in[3];
    const float* e1_w2   = (const float*)d_in[4];
    const float* e1_b2   = (const float*)d_in[5];
    const float* root1   = (const float*)d_in[6];
    const float* bias1   = (const float*)d_in[7];
    const float* e2_w1   = (const float*)d_in[8];
    const float* e2_b1   = (const float*)d_in[9];
    const float* e2_w2   = (const float*)d_in[10];
    const float* e2_b2   = (const float*)d_in[11];
    const float* root2   = (const float*)d_in[12];
    const float* bias2   = (const float*)d_in[13];
    const float* bn1_g   = (const float*)d_in[14];
    const float* bn1_b   = (const float*)d_in[15];
    const float* bn1_m   = (const float*)d_in[16];
    const float* bn1_v   = (const float*)d_in[17];
    const float* bn2_g   = (const float*)d_in[18];
    const float* bn2_b   = (const float*)d_in[19];
    const float* bn2_m   = (const float*)d_in[20];
    const float* bn2_v   = (const float*)d_in[21];
    const float* r1_w    = (const float*)d_in[22];
    const float* r1_b    = (const float*)d_in[23];
    const float* r2_w    = (const float*)d_in[24];
    const float* r2_b    = (const float*)d_in[25];
    const int*   ei      = (const int*)d_in[26];
    const int*   batch   = (const int*)d_in[27];

    char* ws = (char*)d_ws;

    // zero the barrier slots (everything else is zeroed in-kernel)
    hipMemsetAsync(ws + OFF_BARS, 0, 64, stream);

    k_mega<<<NBLK, 256, 0, stream>>>(
        x, eattr,
        e1_w1, e1_b1, e2_w1, e2_b1,
        e1_w2, e1_b2, e2_w2, e2_b2,
        root1, bias1, root2, bias2,
        bn1_g, bn1_b, bn1_m, bn1_v,
        bn2_g, bn2_b, bn2_m, bn2_v,
        r1_w, r1_b, r2_w, r2_b,
        ei, batch, (float*)d_out, ws);
}

// Round 8
// 263.197 us; speedup vs baseline: 3.7910x; 3.7910x over previous
//
#include <hip/hip_runtime.h>

#define NN 10000
#define EE 100000
#define GG 64
#define EPSV 1e-5f
#define SLOTS 1056         // 32*32 P-slots + 32 bias slots (w2r layout [i][slot])
#define PST 36             // P2 c-stride per o-row (c=0..31 data, 32 bias, 33..35 pad)
#define PNODE (32*PST)     // 1152 floats per node in LDS
#define HBLK 391           // ceil(EE/256) hist blocks in k_pre
#define WBLK 160           // w2t blocks in k_pre: 5 per i, i=0..31
#define NBK 1250           // node blocks (8 nodes each)

// workspace offsets (bytes, 16B-aligned)
#define OFF_W2R1   0
#define OFF_W2R2   135168
#define OFF_MSG1   270336       // 12,800,000
#define OFF_MSG2   13070336     // 12,800,000
#define OFF_EACSR  25870336     // 1,600,000
// ---- zero region start (88,256 B) ----
#define OFF_CNT    27470336     // 40,000
#define OFF_DEG    27510336     // 40,000
#define OFF_PSUM   27550336     // 8,192
#define OFF_DONE   27558528     // 64
// ---- zero region end ----
#define OFF_XMID   27558592     // 1,280,000
#define OFF_ROWPTR 28838592     // 40,064
#define OFF_CURSOR 28878656     // 40,000
#define OFF_COLPTR 28918656     // 40,064
#define OFF_CCUR   28958720     // 40,000
#define OFF_MSRC   28998720     // 400,000
#define OFF_CPOS   29398720     // 400,000  -> total ~29.8 MB

// ---------------- k_pre: degree histograms + weight transposes (R5 verbatim) --------
__global__ __launch_bounds__(256) void k_pre(const int* __restrict__ ei,
        int* __restrict__ cnt, int* __restrict__ deg,
        const float* __restrict__ w2a, const float* __restrict__ b2a,
        const float* __restrict__ w2b, const float* __restrict__ b2b,
        float* __restrict__ w2r1, float* __restrict__ w2r2) {
    int blk = blockIdx.x;
    int t = threadIdx.x;
    if (blk < HBLK) {
        int e = blk * 256 + t;
        if (e < EE) {
            atomicAdd(&cnt[ei[EE + e]], 1);   // dst in-degree
            atomicAdd(&deg[ei[e]], 1);        // src out-degree
        }
    } else {
        int b2i = blk - HBLK;                 // 0..159
        int s = (b2i % 5) * 256 + t;
        int i = b2i / 5;
        if (s < SLOTS) {
            float va = (s < 1024) ? w2a[(s >> 5) * 1024 + i * 32 + (s & 31)]
                                  : b2a[i * 32 + (s - 1024)];
            float vb = (s < 1024) ? w2b[(s >> 5) * 1024 + i * 32 + (s & 31)]
                                  : b2b[i * 32 + (s - 1024)];
            w2r1[i * SLOTS + s] = va;
            w2r2[i * SLOTS + s] = vb;
        }
    }
}

// -------- scan: 2 parallel blocks (block 0: deg->rowptr/cursor; block 1: cnt->colptr/ccursor)
__global__ __launch_bounds__(1024) void k_scan2(const int* __restrict__ deg,
                                                const int* __restrict__ cnt,
                                                int* __restrict__ rowptr,
                                                int* __restrict__ cursor,
                                                int* __restrict__ colptr,
                                                int* __restrict__ ccursor) {
    __shared__ int buf[1024];
    int pass = blockIdx.x;
    const int* src = pass ? cnt : deg;
    int* dst_p = pass ? colptr : rowptr;
    int* dst_c = pass ? ccursor : cursor;
    int t = threadIdx.x;
    int base = t * 10;
    int v[10]; int s = 0;
    #pragma unroll
    for (int k = 0; k < 10; k++) {
        int idx = base + k;
        v[k] = (idx < NN) ? src[idx] : 0;
        s += v[k];
    }
    buf[t] = s;
    for (int off = 1; off < 1024; off <<= 1) {
        __syncthreads();
        int val = buf[t] + ((t >= off) ? buf[t - off] : 0);
        __syncthreads();
        buf[t] = val;
    }
    __syncthreads();
    int carry = (t > 0) ? buf[t - 1] : 0;
    #pragma unroll
    for (int k = 0; k < 10; k++) {
        int idx = base + k;
        if (idx < NN) { dst_p[idx] = carry; dst_c[idx] = carry; }
        carry += v[k];
    }
    if (t == 1023) dst_p[NN] = buf[1023];
}

// ---------------- scatter: CSR slots + ea_csr + msrc + CSC pos list (R5 verbatim) -----
__global__ void k_scatter(const int* __restrict__ ei,
        const float* __restrict__ edge_attr,
        int* __restrict__ cursor, int* __restrict__ ccursor,
        int* __restrict__ msrc, int* __restrict__ cpos,
        float4* __restrict__ ea_csr) {
    int e = blockIdx.x * 256 + threadIdx.x;
    if (e >= EE) return;
    int sn = ei[e];
    int dn = ei[EE + e];
    float4 a = *(const float4*)&edge_attr[(size_t)e * 4];
    int pos = atomicAdd(&cursor[sn], 1);
    msrc[pos] = sn;
    ea_csr[pos] = a;
    int cp = atomicAdd(&ccursor[dn], 1);
    cpos[cp] = pos;
}

// ---------------- k_f1: layer-1 NNConv (R5 k_fused3 verbatim) -------------------------
__global__ __launch_bounds__(256, 3) void k_f1(const float* __restrict__ x,
        const float4* __restrict__ ea_csr,
        const float* __restrict__ w1, const float* __restrict__ b1,
        const float* __restrict__ w2r,
        const int* __restrict__ msrc, const int* __restrict__ rowptr,
        float* __restrict__ msg) {
    __shared__ float xs[8][32];          // 1,024 B
    __shared__ float P2[8 * PNODE];      // 36,864 B
    __shared__ float shx[8][32];         // 1,024 B  (total 38,912 -> 4 blocks/CU)
    int t = threadIdx.x;
    int o = t & 31;
    int cb = 4 * (t >> 5);
    int n0 = blockIdx.x * 8;

    int ebase = rowptr[n0];
    int eend  = rowptr[n0 + 8];
    int grp = t >> 5;

    float wc0 = w1[o], wc1 = w1[32 + o], wc2 = w1[64 + o], wc3 = w1[96 + o];
    float bb  = b1[o];

    int pos = ebase + grp;
    float4 aC = make_float4(0.f, 0.f, 0.f, 0.f);
    int srcC = n0;
    if (pos < eend) { aC = ea_csr[pos]; srcC = msrc[pos]; }

    xs[grp][o] = x[n0 * 32 + t];
    __syncthreads();

    // ---- Phase A ----
    {
        float acc[4][8];
        #pragma unroll
        for (int k = 0; k < 4; k++)
            #pragma unroll
            for (int n = 0; n < 8; n++) acc[k][n] = 0.f;
        #pragma unroll
        for (int j = 0; j < 8; j++) {
            float wk[4][4];
            #pragma unroll
            for (int r = 0; r < 4; r++)
                #pragma unroll
                for (int k = 0; k < 4; k++)
                    wk[r][k] = w2r[(4 * j + r) * SLOTS + (cb + k) * 32 + o];
            #pragma unroll
            for (int n = 0; n < 8; n++) {
                float4 xq = *(const float4*)&xs[n][4 * j];
                #pragma unroll
                for (int k = 0; k < 4; k++)
                    acc[k][n] += xq.x * wk[0][k] + xq.y * wk[1][k]
                               + xq.z * wk[2][k] + xq.w * wk[3][k];
            }
        }
        #pragma unroll
        for (int n = 0; n < 8; n++) {
            float4 st = make_float4(acc[0][n], acc[1][n], acc[2][n], acc[3][n]);
            *(float4*)&P2[n * PNODE + o * PST + cb] = st;
        }
    }
    if (t < 32) {
        float wb[32];
        #pragma unroll
        for (int i = 0; i < 32; i++) wb[i] = w2r[i * SLOTS + 1024 + t];
        #pragma unroll
        for (int n = 0; n < 8; n++) {
            float b = 0.f;
            #pragma unroll
            for (int j = 0; j < 8; j++) {
                float4 xq = *(const float4*)&xs[n][4 * j];
                b += xq.x * wb[4 * j] + xq.y * wb[4 * j + 1]
                   + xq.z * wb[4 * j + 2] + xq.w * wb[4 * j + 3];
            }
            *(float4*)&P2[n * PNODE + t * PST + 32] = make_float4(b, 0.f, 0.f, 0.f);
        }
    }
    __syncthreads();

    // ---- Phase B ----
    while (pos < eend) {
        int pn = pos + 8;
        float4 aN = aC; int srcN = srcC;
        if (pn < eend) { aN = ea_csr[pn]; srcN = msrc[pn]; }
        float h = fmaxf(aC.x * wc0 + aC.y * wc1 + aC.z * wc2 + aC.w * wc3 + bb, 0.f);
        shx[grp][o] = h;
        asm volatile("" ::: "memory");
        const float* Pn = &P2[(srcC - n0) * PNODE + o * PST];
        float m = Pn[32];
        #pragma unroll
        for (int b = 0; b < 8; b++) {
            float4 hx = *(const float4*)&shx[grp][4 * b];
            float4 pq = *(const float4*)&Pn[4 * b];
            m += hx.x * pq.x + hx.y * pq.y + hx.z * pq.z + hx.w * pq.w;
        }
        msg[(size_t)pos * 32 + o] = m;
        asm volatile("" ::: "memory");
        pos = pn; aC = aN; srcC = srcN;
    }
}

// ---------------- k_mid: combine-L1 (msg1 gather -> xmid) + fused3-L2 (-> msg2) -------
// A block's layer-2 Phase A needs only its own 8 nodes' xmid, which its combine-L1
// produces -> xmid stays in LDS; one dispatch boundary removed.
__global__ __launch_bounds__(256, 3) void k_mid(const float* __restrict__ x,
        const float* __restrict__ msg1,
        const int* __restrict__ colptr, const int* __restrict__ cpos,
        const float* __restrict__ root1, const float* __restrict__ bias1,
        const float* __restrict__ bn1g, const float* __restrict__ bn1b,
        const float* __restrict__ bn1m, const float* __restrict__ bn1v,
        const float4* __restrict__ ea_csr,
        const float* __restrict__ w1, const float* __restrict__ b1,
        const float* __restrict__ w2r,
        const int* __restrict__ msrc, const int* __restrict__ rowptr,
        float* __restrict__ xmid, float* __restrict__ msg2) {
    __shared__ float xs[8][32];          // 1,024 B
    __shared__ float P2[8 * PNODE];      // 36,864 B
    __shared__ float shx[8][32];         // 1,024 B
    __shared__ float xmid_s[8][32];      // 1,024 B  (total 39,936 -> 4 blocks/CU)
    int t = threadIdx.x;
    int o = t & 31;
    int grp = t >> 5;
    int cb = 4 * grp;
    int n0 = blockIdx.x * 8;

    int ebase = rowptr[n0];
    int eend  = rowptr[n0 + 8];

    // layer-2 h weights + first-edge prefetch (held through combine + Phase A)
    float wc0 = w1[o], wc1 = w1[32 + o], wc2 = w1[64 + o], wc3 = w1[96 + o];
    float hbb = b1[o];
    int pos = ebase + grp;
    float4 aC = make_float4(0.f, 0.f, 0.f, 0.f);
    int srcC = n0;
    if (pos < eend) { aC = ea_csr[pos]; srcC = msrc[pos]; }

    // ---- combine-L1 for node n0+grp ----
    xs[grp][o] = x[n0 * 32 + t];
    __syncthreads();
    {
        int k = grp, n = n0 + k;
        float rt = bias1[o];
        #pragma unroll
        for (int i = 0; i < 32; i++) rt += xs[k][i] * root1[i * 32 + o];
        int jbase = colptr[n], jend = colptr[n + 1];
        float acc = 0.f;
        for (int jb = jbase; jb < jend; jb += 32) {
            int nrem = jend - jb;
            int lim = (nrem < 32) ? nrem : 32;
            int cv = 0;
            if (o < lim) cv = cpos[jb + o];
            for (int j = 0; j < lim; j += 8) {
                float v[8];
                #pragma unroll
                for (int q = 0; q < 8; q++) {
                    if (j + q < lim) {
                        int cj = __shfl(cv, j + q, 32);
                        v[q] = msg1[(size_t)cj * 32 + o];
                    } else v[q] = 0.f;
                }
                #pragma unroll
                for (int q = 0; q < 8; q++) acc += v[q];
            }
        }
        float a = acc / fmaxf((float)(jend - jbase), 1.f);
        float val = a + rt;
        val = (val - bn1m[o]) * rsqrtf(bn1v[o] + EPSV) * bn1g[o] + bn1b[o];
        val = fmaxf(val, 0.f);
        xmid_s[k][o] = val;
        xmid[(size_t)n * 32 + o] = val;      // k_end needs it for the root2 term
    }
    __syncthreads();

    // ---- Phase A (layer 2) from xmid_s ----
    {
        float acc[4][8];
        #pragma unroll
        for (int k = 0; k < 4; k++)
            #pragma unroll
            for (int n = 0; n < 8; n++) acc[k][n] = 0.f;
        #pragma unroll
        for (int j = 0; j < 8; j++) {
            float wk[4][4];
            #pragma unroll
            for (int r = 0; r < 4; r++)
                #pragma unroll
                for (int k = 0; k < 4; k++)
                    wk[r][k] = w2r[(4 * j + r) * SLOTS + (cb + k) * 32 + o];
            #pragma unroll
            for (int n = 0; n < 8; n++) {
                float4 xq = *(const float4*)&xmid_s[n][4 * j];
                #pragma unroll
                for (int k = 0; k < 4; k++)
                    acc[k][n] += xq.x * wk[0][k] + xq.y * wk[1][k]
                               + xq.z * wk[2][k] + xq.w * wk[3][k];
            }
        }
        #pragma unroll
        for (int n = 0; n < 8; n++) {
            float4 st = make_float4(acc[0][n], acc[1][n], acc[2][n], acc[3][n]);
            *(float4*)&P2[n * PNODE + o * PST + cb] = st;
        }
    }
    if (t < 32) {
        float wb[32];
        #pragma unroll
        for (int i = 0; i < 32; i++) wb[i] = w2r[i * SLOTS + 1024 + t];
        #pragma unroll
        for (int n = 0; n < 8; n++) {
            float b = 0.f;
            #pragma unroll
            for (int j = 0; j < 8; j++) {
                float4 xq = *(const float4*)&xmid_s[n][4 * j];
                b += xq.x * wb[4 * j] + xq.y * wb[4 * j + 1]
                   + xq.z * wb[4 * j + 2] + xq.w * wb[4 * j + 3];
            }
            *(float4*)&P2[n * PNODE + t * PST + 32] = make_float4(b, 0.f, 0.f, 0.f);
        }
    }
    __syncthreads();

    // ---- Phase B (layer 2) -> msg2 ----
    while (pos < eend) {
        int pn = pos + 8;
        float4 aN = aC; int srcN = srcC;
        if (pn < eend) { aN = ea_csr[pn]; srcN = msrc[pn]; }
        float h = fmaxf(aC.x * wc0 + aC.y * wc1 + aC.z * wc2 + aC.w * wc3 + hbb, 0.f);
        shx[grp][o] = h;
        asm volatile("" ::: "memory");
        const float* Pn = &P2[(srcC - n0) * PNODE + o * PST];
        float m = Pn[32];
        #pragma unroll
        for (int b = 0; b < 8; b++) {
            float4 hx = *(const float4*)&shx[grp][4 * b];
            float4 pq = *(const float4*)&Pn[4 * b];
            m += hx.x * pq.x + hx.y * pq.y + hx.z * pq.z + hx.w * pq.w;
        }
        msg2[(size_t)pos * 32 + o] = m;
        asm volatile("" ::: "memory");
        pos = pn; aC = aN; srcC = srcN;
    }
}

// ---------------- k_end: combine-L2 + pool atomics; final block does readout ----------
__global__ __launch_bounds__(256) void k_end(const float* __restrict__ xmid,
        const float* __restrict__ msg2,
        const int* __restrict__ colptr, const int* __restrict__ cpos,
        const float* __restrict__ root2, const float* __restrict__ bias2,
        const float* __restrict__ bn2g, const float* __restrict__ bn2b,
        const float* __restrict__ bn2m, const float* __restrict__ bn2v,
        const int* __restrict__ batch, float* __restrict__ psum,
        int* __restrict__ done,
        const float* __restrict__ r1w, const float* __restrict__ r1b,
        const float* __restrict__ r2w, const float* __restrict__ r2b,
        float* __restrict__ out) {
    __shared__ float xs[8][32];
    __shared__ float vals[8][32];
    __shared__ int gb[8];
    __shared__ float rd[2592];           // readout scratch (last block only)
    __shared__ int lastflag;
    int t = threadIdx.x;
    int o = t & 31;
    int grp = t >> 5;
    int n0 = blockIdx.x * 8;

    xs[grp][o] = xmid[(size_t)n0 * 32 + t];
    __syncthreads();
    int k = grp, n = n0 + k;
    float rt = bias2[o];
    #pragma unroll
    for (int i = 0; i < 32; i++) rt += xs[k][i] * root2[i * 32 + o];
    int jbase = colptr[n], jend = colptr[n + 1];
    float acc = 0.f;
    for (int jb = jbase; jb < jend; jb += 32) {
        int nrem = jend - jb;
        int lim = (nrem < 32) ? nrem : 32;
        int cv = 0;
        if (o < lim) cv = cpos[jb + o];
        for (int j = 0; j < lim; j += 8) {
            float v[8];
            #pragma unroll
            for (int q = 0; q < 8; q++) {
                if (j + q < lim) {
                    int cj = __shfl(cv, j + q, 32);
                    v[q] = msg2[(size_t)cj * 32 + o];
                } else v[q] = 0.f;
            }
            #pragma unroll
            for (int q = 0; q < 8; q++) acc += v[q];
        }
    }
    float a = acc / fmaxf((float)(jend - jbase), 1.f);
    float val = a + rt;
    val = (val - bn2m[o]) * rsqrtf(bn2v[o] + EPSV) * bn2g[o] + bn2b[o];
    val = fmaxf(val, 0.f);
    vals[k][o] = val;
    if (o == 0) gb[k] = batch[n];
    __syncthreads();
    if (k == 0) {
        float pacc = vals[0][o];
        int g = gb[0];
        #pragma unroll
        for (int k2 = 1; k2 < 8; k2++) {
            if (gb[k2] == g) pacc += vals[k2][o];
            else {
                atomicAdd(&psum[(size_t)g * 32 + o], pacc);
                g = gb[k2]; pacc = vals[k2][o];
            }
        }
        atomicAdd(&psum[(size_t)g * 32 + o], pacc);
    }
    __syncthreads();                     // psum atomics drained (vmcnt 0 at barrier)

    // ---- last-block readout: one atomicAdd per block, NO spinning ----
    if (t == 0) {
        __threadfence();                 // release
        int old = atomicAdd(done, 1);
        lastflag = (old == NBK - 1);
    }
    __syncthreads();
    if (!lastflag) return;
    __threadfence();                     // acquire: invalidate stale cached lines

    float* w1s = rd;                     // 512
    float* b1s = rd + 512;               // 16
    float* w2s = rd + 528;               // 16
    float* ps  = rd + 544;               // 2048
    int cnt_g = 0;
    if (t < GG) {
        int lo = 0, hi = NN;
        while (lo < hi) { int m2 = (lo + hi) >> 1; if (batch[m2] < t) lo = m2 + 1; else hi = m2; }
        int lb = lo;
        lo = 0; hi = NN;
        while (lo < hi) { int m2 = (lo + hi) >> 1; if (batch[m2] < t + 1) lo = m2 + 1; else hi = m2; }
        cnt_g = lo - lb;
    }
    w1s[t] = r1w[t];
    w1s[t + 256] = r1w[t + 256];
    if (t < 16) { b1s[t] = r1b[t]; w2s[t] = r2w[t]; }
    #pragma unroll
    for (int i = 0; i < GG * 32 / 256; i++)
        ps[t + i * 256] = __hip_atomic_load(&psum[t + i * 256], __ATOMIC_RELAXED,
                                            __HIP_MEMORY_SCOPE_AGENT);
    __syncthreads();
    if (t < GG) {
        float inv = 1.f / fmaxf((float)cnt_g, 1.f);
        float acc2 = r2b[0];
        #pragma unroll
        for (int j = 0; j < 16; j++) {
            float dot = 0.f;
            #pragma unroll
            for (int c = 0; c < 32; c++) dot += ps[t * 32 + c] * w1s[c * 16 + j];
            float z = dot * inv + b1s[j];
            acc2 += fmaxf(z, 0.f) * w2s[j];
        }
        out[t] = acc2;
    }
}

extern "C" void kernel_launch(void* const* d_in, const int* in_sizes, int n_in,
                              void* d_out, int out_size, void* d_ws, size_t ws_size,
                              hipStream_t stream) {
    const float* x       = (const float*)d_in[0];
    const float* eattr   = (const float*)d_in[1];
    const float* e1_w1   = (const float*)d_in[2];
    const float* e1_b1   = (const float*)d_in[3];
    const float* e1_w2   = (const float*)d_in[4];
    const float* e1_b2   = (const float*)d_in[5];
    const float* root1   = (const float*)d_in[6];
    const float* bias1   = (const float*)d_in[7];
    const float* e2_w1   = (const float*)d_in[8];
    const float* e2_b1   = (const float*)d_in[9];
    const float* e2_w2   = (const float*)d_in[10];
    const float* e2_b2   = (const float*)d_in[11];
    const float* root2   = (const float*)d_in[12];
    const float* bias2   = (const float*)d_in[13];
    const float* bn1_g   = (const float*)d_in[14];
    const float* bn1_b   = (const float*)d_in[15];
    const float* bn1_m   = (const float*)d_in[16];
    const float* bn1_v   = (const float*)d_in[17];
    const float* bn2_g   = (const float*)d_in[18];
    const float* bn2_b   = (const float*)d_in[19];
    const float* bn2_m   = (const float*)d_in[20];
    const float* bn2_v   = (const float*)d_in[21];
    const float* r1_w    = (const float*)d_in[22];
    const float* r1_b    = (const float*)d_in[23];
    const float* r2_w    = (const float*)d_in[24];
    const float* r2_b    = (const float*)d_in[25];
    const int*   ei      = (const int*)d_in[26];
    const int*   batch   = (const int*)d_in[27];

    char* ws = (char*)d_ws;
    float*  w2r1   = (float*) (ws + OFF_W2R1);
    float*  w2r2   = (float*) (ws + OFF_W2R2);
    float*  msg1   = (float*) (ws + OFF_MSG1);
    float*  msg2   = (float*) (ws + OFF_MSG2);
    float4* ea_csr = (float4*)(ws + OFF_EACSR);
    int*    cnt    = (int*)   (ws + OFF_CNT);
    int*    deg    = (int*)   (ws + OFF_DEG);
    float*  psum   = (float*) (ws + OFF_PSUM);
    int*    done   = (int*)   (ws + OFF_DONE);
    float*  xmid   = (float*) (ws + OFF_XMID);
    int*    rowptr = (int*)   (ws + OFF_ROWPTR);
    int*    cursor = (int*)   (ws + OFF_CURSOR);
    int*    colptr = (int*)   (ws + OFF_COLPTR);
    int*    ccursor= (int*)   (ws + OFF_CCUR);
    int*    msrc   = (int*)   (ws + OFF_MSRC);
    int*    cpos   = (int*)   (ws + OFF_CPOS);

    hipMemsetAsync(ws + OFF_CNT, 0, 88256, stream);   // cnt+deg+psum+done

    k_pre<<<HBLK + WBLK, 256, 0, stream>>>(ei, cnt, deg,
                                           e1_w2, e1_b2, e2_w2, e2_b2, w2r1, w2r2);
    k_scan2<<<2, 1024, 0, stream>>>(deg, cnt, rowptr, cursor, colptr, ccursor);
    k_scatter<<<(EE + 255) / 256, 256, 0, stream>>>(ei, eattr,
                                                    cursor, ccursor, msrc, cpos,
                                                    ea_csr);

    k_f1<<<NBK, 256, 0, stream>>>(x, ea_csr, e1_w1, e1_b1, w2r1,
                                  msrc, rowptr, msg1);
    k_mid<<<NBK, 256, 0, stream>>>(x, msg1, colptr, cpos, root1, bias1,
                                   bn1_g, bn1_b, bn1_m, bn1_v,
                                   ea_csr, e2_w1, e2_b1, w2r2,
                                   msrc, rowptr, xmid, msg2);
    k_end<<<NBK, 256, 0, stream>>>(xmid, msg2, colptr, cpos, root2, bias2,
                                   bn2_g, bn2_b, bn2_m, bn2_v,
                                   batch, psum, done,
                                   r1_w, r1_b, r2_w, r2_b, (float*)d_out);
}

// Round 9
// 261.687 us; speedup vs baseline: 3.8129x; 1.0058x over previous
//
#include <hip/hip_runtime.h>

#define NN 10000
#define EE 100000
#define GG 64
#define EPSV 1e-5f
#define SLOTS 1056         // 32*32 P-slots + 32 bias slots (w2r layout [i][slot])
#define PST 36             // P2 c-stride per o-row (c=0..31 data, 32 bias, 33..35 pad)
#define PNODE (32*PST)     // 1152 floats per node in LDS
#define HBLK 391           // ceil(EE/256) hist blocks in k_pre
#define WBLK 160           // w2t blocks in k_pre: 5 per i, i=0..31
#define NBK 1250           // node blocks (8 nodes each)

// workspace offsets (bytes, 16B-aligned)
#define OFF_W2R1   0
#define OFF_W2R2   135168
#define OFF_MSG1   270336       // 12,800,000  (CSC-slot order!)
#define OFF_MSG2   13070336     // 12,800,000  (CSC-slot order!)
#define OFF_EACSR  25870336     // 1,600,000
// ---- zero region start (88,256 B) ----
#define OFF_CNT    27470336     // 40,000
#define OFF_DEG    27510336     // 40,000
#define OFF_PSUM   27550336     // 8,192
#define OFF_DONE   27558528     // 64
// ---- zero region end ----
#define OFF_XMID   27558592     // 1,280,000
#define OFF_ROWPTR 28838592     // 40,064
#define OFF_CURSOR 28878656     // 40,000
#define OFF_COLPTR 28918656     // 40,064
#define OFF_CCUR   28958720     // 40,000
#define OFF_META   28998720     // 800,000 (int2: src, cscslot)  -> total ~29.8 MB

// ---------------- k_pre: degree histograms + weight transposes --------
__global__ __launch_bounds__(256) void k_pre(const int* __restrict__ ei,
        int* __restrict__ cnt, int* __restrict__ deg,
        const float* __restrict__ w2a, const float* __restrict__ b2a,
        const float* __restrict__ w2b, const float* __restrict__ b2b,
        float* __restrict__ w2r1, float* __restrict__ w2r2) {
    int blk = blockIdx.x;
    int t = threadIdx.x;
    if (blk < HBLK) {
        int e = blk * 256 + t;
        if (e < EE) {
            atomicAdd(&cnt[ei[EE + e]], 1);   // dst in-degree
            atomicAdd(&deg[ei[e]], 1);        // src out-degree
        }
    } else {
        int b2i = blk - HBLK;                 // 0..159
        int s = (b2i % 5) * 256 + t;
        int i = b2i / 5;
        if (s < SLOTS) {
            float va = (s < 1024) ? w2a[(s >> 5) * 1024 + i * 32 + (s & 31)]
                                  : b2a[i * 32 + (s - 1024)];
            float vb = (s < 1024) ? w2b[(s >> 5) * 1024 + i * 32 + (s & 31)]
                                  : b2b[i * 32 + (s - 1024)];
            w2r1[i * SLOTS + s] = va;
            w2r2[i * SLOTS + s] = vb;
        }
    }
}

// -------- scan: 2 parallel blocks (block 0: deg->rowptr/cursor; block 1: cnt->colptr/ccursor)
__global__ __launch_bounds__(1024) void k_scan2(const int* __restrict__ deg,
                                                const int* __restrict__ cnt,
                                                int* __restrict__ rowptr,
                                                int* __restrict__ cursor,
                                                int* __restrict__ colptr,
                                                int* __restrict__ ccursor) {
    __shared__ int buf[1024];
    int pass = blockIdx.x;
    const int* src = pass ? cnt : deg;
    int* dst_p = pass ? colptr : rowptr;
    int* dst_c = pass ? ccursor : cursor;
    int t = threadIdx.x;
    int base = t * 10;
    int v[10]; int s = 0;
    #pragma unroll
    for (int k = 0; k < 10; k++) {
        int idx = base + k;
        v[k] = (idx < NN) ? src[idx] : 0;
        s += v[k];
    }
    buf[t] = s;
    for (int off = 1; off < 1024; off <<= 1) {
        __syncthreads();
        int val = buf[t] + ((t >= off) ? buf[t - off] : 0);
        __syncthreads();
        buf[t] = val;
    }
    __syncthreads();
    int carry = (t > 0) ? buf[t - 1] : 0;
    #pragma unroll
    for (int k = 0; k < 10; k++) {
        int idx = base + k;
        if (idx < NN) { dst_p[idx] = carry; dst_c[idx] = carry; }
        carry += v[k];
    }
    if (t == 1023) dst_p[NN] = buf[1023];
}

// ---------------- scatter: CSR slots + ea_csr + meta(src, CSC slot) -------------------
// R9: messages will be STORED at the edge's CSC slot (dst-sorted), so combine reads
// them as a contiguous stream. meta[pos] packs (src, cscslot) for Phase B.
__global__ void k_scatter(const int* __restrict__ ei,
        const float* __restrict__ edge_attr,
        int* __restrict__ cursor, int* __restrict__ ccursor,
        int2* __restrict__ meta, float4* __restrict__ ea_csr) {
    int e = blockIdx.x * 256 + threadIdx.x;
    if (e >= EE) return;
    int sn = ei[e];
    int dn = ei[EE + e];
    float4 a = *(const float4*)&edge_attr[(size_t)e * 4];
    int pos = atomicAdd(&cursor[sn], 1);
    int cs  = atomicAdd(&ccursor[dn], 1);
    meta[pos] = make_int2(sn, cs);
    ea_csr[pos] = a;
}

// ---------------- k_f1: layer-1 NNConv; msg written at CSC slot -----------------------
__global__ __launch_bounds__(256, 3) void k_f1(const float* __restrict__ x,
        const float4* __restrict__ ea_csr,
        const float* __restrict__ w1, const float* __restrict__ b1,
        const float* __restrict__ w2r,
        const int2* __restrict__ meta, const int* __restrict__ rowptr,
        float* __restrict__ msg) {
    __shared__ float xs[8][32];          // 1,024 B
    __shared__ float P2[8 * PNODE];      // 36,864 B
    __shared__ float shx[8][32];         // 1,024 B  (total 38,912 -> 4 blocks/CU)
    int t = threadIdx.x;
    int o = t & 31;
    int cb = 4 * (t >> 5);
    int n0 = blockIdx.x * 8;

    int ebase = rowptr[n0];
    int eend  = rowptr[n0 + 8];
    int grp = t >> 5;

    float wc0 = w1[o], wc1 = w1[32 + o], wc2 = w1[64 + o], wc3 = w1[96 + o];
    float bb  = b1[o];

    int pos = ebase + grp;
    float4 aC = make_float4(0.f, 0.f, 0.f, 0.f);
    int2 mC = make_int2(n0, 0);
    if (pos < eend) { aC = ea_csr[pos]; mC = meta[pos]; }

    xs[grp][o] = x[n0 * 32 + t];
    __syncthreads();

    // ---- Phase A ----
    {
        float acc[4][8];
        #pragma unroll
        for (int k = 0; k < 4; k++)
            #pragma unroll
            for (int n = 0; n < 8; n++) acc[k][n] = 0.f;
        #pragma unroll
        for (int j = 0; j < 8; j++) {
            float wk[4][4];
            #pragma unroll
            for (int r = 0; r < 4; r++)
                #pragma unroll
                for (int k = 0; k < 4; k++)
                    wk[r][k] = w2r[(4 * j + r) * SLOTS + (cb + k) * 32 + o];
            #pragma unroll
            for (int n = 0; n < 8; n++) {
                float4 xq = *(const float4*)&xs[n][4 * j];
                #pragma unroll
                for (int k = 0; k < 4; k++)
                    acc[k][n] += xq.x * wk[0][k] + xq.y * wk[1][k]
                               + xq.z * wk[2][k] + xq.w * wk[3][k];
            }
        }
        #pragma unroll
        for (int n = 0; n < 8; n++) {
            float4 st = make_float4(acc[0][n], acc[1][n], acc[2][n], acc[3][n]);
            *(float4*)&P2[n * PNODE + o * PST + cb] = st;
        }
    }
    if (t < 32) {
        float wb[32];
        #pragma unroll
        for (int i = 0; i < 32; i++) wb[i] = w2r[i * SLOTS + 1024 + t];
        #pragma unroll
        for (int n = 0; n < 8; n++) {
            float b = 0.f;
            #pragma unroll
            for (int j = 0; j < 8; j++) {
                float4 xq = *(const float4*)&xs[n][4 * j];
                b += xq.x * wb[4 * j] + xq.y * wb[4 * j + 1]
                   + xq.z * wb[4 * j + 2] + xq.w * wb[4 * j + 3];
            }
            *(float4*)&P2[n * PNODE + t * PST + 32] = make_float4(b, 0.f, 0.f, 0.f);
        }
    }
    __syncthreads();

    // ---- Phase B: compute msg, store at CSC slot (posted scatter-store) ----
    while (pos < eend) {
        int pn = pos + 8;
        float4 aN = aC; int2 mN = mC;
        if (pn < eend) { aN = ea_csr[pn]; mN = meta[pn]; }
        float h = fmaxf(aC.x * wc0 + aC.y * wc1 + aC.z * wc2 + aC.w * wc3 + bb, 0.f);
        shx[grp][o] = h;
        asm volatile("" ::: "memory");
        const float* Pn = &P2[(mC.x - n0) * PNODE + o * PST];
        float m = Pn[32];
        #pragma unroll
        for (int b = 0; b < 8; b++) {
            float4 hx = *(const float4*)&shx[grp][4 * b];
            float4 pq = *(const float4*)&Pn[4 * b];
            m += hx.x * pq.x + hx.y * pq.y + hx.z * pq.z + hx.w * pq.w;
        }
        msg[(size_t)mC.y * 32 + o] = m;      // one 128B line per group @ CSC slot
        asm volatile("" ::: "memory");
        pos = pn; aC = aN; mC = mN;
    }
}

// ---------------- k_mid: combine-L1 (linear msg1 stream) + fused3-L2 (-> msg2) --------
__global__ __launch_bounds__(256, 3) void k_mid(const float* __restrict__ x,
        const float* __restrict__ msg1,
        const int* __restrict__ colptr,
        const float* __restrict__ root1, const float* __restrict__ bias1,
        const float* __restrict__ bn1g, const float* __restrict__ bn1b,
        const float* __restrict__ bn1m, const float* __restrict__ bn1v,
        const float4* __restrict__ ea_csr,
        const float* __restrict__ w1, const float* __restrict__ b1,
        const float* __restrict__ w2r,
        const int2* __restrict__ meta, const int* __restrict__ rowptr,
        float* __restrict__ xmid, float* __restrict__ msg2) {
    __shared__ float xs[8][32];          // 1,024 B
    __shared__ float P2[8 * PNODE];      // 36,864 B
    __shared__ float shx[8][32];         // 1,024 B
    __shared__ float xmid_s[8][32];      // 1,024 B  (total 39,936 -> 4 blocks/CU)
    int t = threadIdx.x;
    int o = t & 31;
    int grp = t >> 5;
    int cb = 4 * grp;
    int n0 = blockIdx.x * 8;

    int ebase = rowptr[n0];
    int eend  = rowptr[n0 + 8];

    float wc0 = w1[o], wc1 = w1[32 + o], wc2 = w1[64 + o], wc3 = w1[96 + o];
    float hbb = b1[o];
    int pos = ebase + grp;
    float4 aC = make_float4(0.f, 0.f, 0.f, 0.f);
    int2 mC = make_int2(n0, 0);
    if (pos < eend) { aC = ea_csr[pos]; mC = meta[pos]; }

    // ---- combine-L1 for node n0+grp: CONTIGUOUS msg1 stream ----
    xs[grp][o] = x[n0 * 32 + t];
    __syncthreads();
    {
        int k = grp, n = n0 + k;
        float rt = bias1[o];
        #pragma unroll
        for (int i = 0; i < 32; i++) rt += xs[k][i] * root1[i * 32 + o];
        int jbase = colptr[n], jend = colptr[n + 1];
        float acc = 0.f;
        int j = jbase;
        for (; j + 8 <= jend; j += 8) {
            float v0 = msg1[(size_t)(j + 0) * 32 + o];
            float v1 = msg1[(size_t)(j + 1) * 32 + o];
            float v2 = msg1[(size_t)(j + 2) * 32 + o];
            float v3 = msg1[(size_t)(j + 3) * 32 + o];
            float v4 = msg1[(size_t)(j + 4) * 32 + o];
            float v5 = msg1[(size_t)(j + 5) * 32 + o];
            float v6 = msg1[(size_t)(j + 6) * 32 + o];
            float v7 = msg1[(size_t)(j + 7) * 32 + o];
            acc += ((v0 + v1) + (v2 + v3)) + ((v4 + v5) + (v6 + v7));
        }
        for (; j < jend; j++) acc += msg1[(size_t)j * 32 + o];
        float a = acc / fmaxf((float)(jend - jbase), 1.f);
        float val = a + rt;
        val = (val - bn1m[o]) * rsqrtf(bn1v[o] + EPSV) * bn1g[o] + bn1b[o];
        val = fmaxf(val, 0.f);
        xmid_s[k][o] = val;
        xmid[(size_t)n * 32 + o] = val;      // k_end needs it for the root2 term
    }
    __syncthreads();

    // ---- Phase A (layer 2) from xmid_s ----
    {
        float acc[4][8];
        #pragma unroll
        for (int k = 0; k < 4; k++)
            #pragma unroll
            for (int n = 0; n < 8; n++) acc[k][n] = 0.f;
        #pragma unroll
        for (int j = 0; j < 8; j++) {
            float wk[4][4];
            #pragma unroll
            for (int r = 0; r < 4; r++)
                #pragma unroll
                for (int k = 0; k < 4; k++)
                    wk[r][k] = w2r[(4 * j + r) * SLOTS + (cb + k) * 32 + o];
            #pragma unroll
            for (int n = 0; n < 8; n++) {
                float4 xq = *(const float4*)&xmid_s[n][4 * j];
                #pragma unroll
                for (int k = 0; k < 4; k++)
                    acc[k][n] += xq.x * wk[0][k] + xq.y * wk[1][k]
                               + xq.z * wk[2][k] + xq.w * wk[3][k];
            }
        }
        #pragma unroll
        for (int n = 0; n < 8; n++) {
            float4 st = make_float4(acc[0][n], acc[1][n], acc[2][n], acc[3][n]);
            *(float4*)&P2[n * PNODE + o * PST + cb] = st;
        }
    }
    if (t < 32) {
        float wb[32];
        #pragma unroll
        for (int i = 0; i < 32; i++) wb[i] = w2r[i * SLOTS + 1024 + t];
        #pragma unroll
        for (int n = 0; n < 8; n++) {
            float b = 0.f;
            #pragma unroll
            for (int j = 0; j < 8; j++) {
                float4 xq = *(const float4*)&xmid_s[n][4 * j];
                b += xq.x * wb[4 * j] + xq.y * wb[4 * j + 1]
                   + xq.z * wb[4 * j + 2] + xq.w * wb[4 * j + 3];
            }
            *(float4*)&P2[n * PNODE + t * PST + 32] = make_float4(b, 0.f, 0.f, 0.f);
        }
    }
    __syncthreads();

    // ---- Phase B (layer 2) -> msg2 @ CSC slots ----
    while (pos < eend) {
        int pn = pos + 8;
        float4 aN = aC; int2 mN = mC;
        if (pn < eend) { aN = ea_csr[pn]; mN = meta[pn]; }
        float h = fmaxf(aC.x * wc0 + aC.y * wc1 + aC.z * wc2 + aC.w * wc3 + hbb, 0.f);
        shx[grp][o] = h;
        asm volatile("" ::: "memory");
        const float* Pn = &P2[(mC.x - n0) * PNODE + o * PST];
        float m = Pn[32];
        #pragma unroll
        for (int b = 0; b < 8; b++) {
            float4 hx = *(const float4*)&shx[grp][4 * b];
            float4 pq = *(const float4*)&Pn[4 * b];
            m += hx.x * pq.x + hx.y * pq.y + hx.z * pq.z + hx.w * pq.w;
        }
        msg2[(size_t)mC.y * 32 + o] = m;
        asm volatile("" ::: "memory");
        pos = pn; aC = aN; mC = mN;
    }
}

// ---------------- k_end: combine-L2 (linear msg2 stream) + pool; last block: readout ---
__global__ __launch_bounds__(256) void k_end(const float* __restrict__ xmid,
        const float* __restrict__ msg2,
        const int* __restrict__ colptr,
        const float* __restrict__ root2, const float* __restrict__ bias2,
        const float* __restrict__ bn2g, const float* __restrict__ bn2b,
        const float* __restrict__ bn2m, const float* __restrict__ bn2v,
        const int* __restrict__ batch, float* __restrict__ psum,
        int* __restrict__ done,
        const float* __restrict__ r1w, const float* __restrict__ r1b,
        const float* __restrict__ r2w, const float* __restrict__ r2b,
        float* __restrict__ out) {
    __shared__ float xs[8][32];
    __shared__ float vals[8][32];
    __shared__ int gb[8];
    __shared__ float rd[2592];           // readout scratch (last block only)
    __shared__ int lastflag;
    int t = threadIdx.x;
    int o = t & 31;
    int grp = t >> 5;
    int n0 = blockIdx.x * 8;

    xs[grp][o] = xmid[(size_t)n0 * 32 + t];
    __syncthreads();
    int k = grp, n = n0 + k;
    float rt = bias2[o];
    #pragma unroll
    for (int i = 0; i < 32; i++) rt += xs[k][i] * root2[i * 32 + o];
    int jbase = colptr[n], jend = colptr[n + 1];
    float acc = 0.f;
    int j = jbase;
    for (; j + 8 <= jend; j += 8) {
        float v0 = msg2[(size_t)(j + 0) * 32 + o];
        float v1 = msg2[(size_t)(j + 1) * 32 + o];
        float v2 = msg2[(size_t)(j + 2) * 32 + o];
        float v3 = msg2[(size_t)(j + 3) * 32 + o];
        float v4 = msg2[(size_t)(j + 4) * 32 + o];
        float v5 = msg2[(size_t)(j + 5) * 32 + o];
        float v6 = msg2[(size_t)(j + 6) * 32 + o];
        float v7 = msg2[(size_t)(j + 7) * 32 + o];
        acc += ((v0 + v1) + (v2 + v3)) + ((v4 + v5) + (v6 + v7));
    }
    for (; j < jend; j++) acc += msg2[(size_t)j * 32 + o];
    float a = acc / fmaxf((float)(jend - jbase), 1.f);
    float val = a + rt;
    val = (val - bn2m[o]) * rsqrtf(bn2v[o] + EPSV) * bn2g[o] + bn2b[o];
    val = fmaxf(val, 0.f);
    vals[k][o] = val;
    if (o == 0) gb[k] = batch[n];
    __syncthreads();
    if (k == 0) {
        float pacc = vals[0][o];
        int g = gb[0];
        #pragma unroll
        for (int k2 = 1; k2 < 8; k2++) {
            if (gb[k2] == g) pacc += vals[k2][o];
            else {
                atomicAdd(&psum[(size_t)g * 32 + o], pacc);
                g = gb[k2]; pacc = vals[k2][o];
            }
        }
        atomicAdd(&psum[(size_t)g * 32 + o], pacc);
    }
    __syncthreads();                     // psum atomics drained

    // ---- last-block readout: one atomicAdd per block, NO spinning ----
    if (t == 0) {
        __threadfence();                 // release
        int old = atomicAdd(done, 1);
        lastflag = (old == NBK - 1);
    }
    __syncthreads();
    if (!lastflag) return;
    __threadfence();                     // acquire

    float* w1s = rd;                     // 512
    float* b1s = rd + 512;               // 16
    float* w2s = rd + 528;               // 16
    float* ps  = rd + 544;               // 2048
    int cnt_g = 0;
    if (t < GG) {
        int lo = 0, hi = NN;
        while (lo < hi) { int m2 = (lo + hi) >> 1; if (batch[m2] < t) lo = m2 + 1; else hi = m2; }
        int lb = lo;
        lo = 0; hi = NN;
        while (lo < hi) { int m2 = (lo + hi) >> 1; if (batch[m2] < t + 1) lo = m2 + 1; else hi = m2; }
        cnt_g = lo - lb;
    }
    w1s[t] = r1w[t];
    w1s[t + 256] = r1w[t + 256];
    if (t < 16) { b1s[t] = r1b[t]; w2s[t] = r2w[t]; }
    #pragma unroll
    for (int i = 0; i < GG * 32 / 256; i++)
        ps[t + i * 256] = __hip_atomic_load(&psum[t + i * 256], __ATOMIC_RELAXED,
                                            __HIP_MEMORY_SCOPE_AGENT);
    __syncthreads();
    if (t < GG) {
        float inv = 1.f / fmaxf((float)cnt_g, 1.f);
        float acc2 = r2b[0];
        #pragma unroll
        for (int jj = 0; jj < 16; jj++) {
            float dot = 0.f;
            #pragma unroll
            for (int c = 0; c < 32; c++) dot += ps[t * 32 + c] * w1s[c * 16 + jj];
            float z = dot * inv + b1s[jj];
            acc2 += fmaxf(z, 0.f) * w2s[jj];
        }
        out[t] = acc2;
    }
}

extern "C" void kernel_launch(void* const* d_in, const int* in_sizes, int n_in,
                              void* d_out, int out_size, void* d_ws, size_t ws_size,
                              hipStream_t stream) {
    const float* x       = (const float*)d_in[0];
    const float* eattr   = (const float*)d_in[1];
    const float* e1_w1   = (const float*)d_in[2];
    const float* e1_b1   = (const float*)d_in[3];
    const float* e1_w2   = (const float*)d_in[4];
    const float* e1_b2   = (const float*)d_in[5];
    const float* root1   = (const float*)d_in[6];
    const float* bias1   = (const float*)d_in[7];
    const float* e2_w1   = (const float*)d_in[8];
    const float* e2_b1   = (const float*)d_in[9];
    const float* e2_w2   = (const float*)d_in[10];
    const float* e2_b2   = (const float*)d_in[11];
    const float* root2   = (const float*)d_in[12];
    const float* bias2   = (const float*)d_in[13];
    const float* bn1_g   = (const float*)d_in[14];
    const float* bn1_b   = (const float*)d_in[15];
    const float* bn1_m   = (const float*)d_in[16];
    const float* bn1_v   = (const float*)d_in[17];
    const float* bn2_g   = (const float*)d_in[18];
    const float* bn2_b   = (const float*)d_in[19];
    const float* bn2_m   = (const float*)d_in[20];
    const float* bn2_v   = (const float*)d_in[21];
    const float* r1_w    = (const float*)d_in[22];
    const float* r1_b    = (const float*)d_in[23];
    const float* r2_w    = (const float*)d_in[24];
    const float* r2_b    = (const float*)d_in[25];
    const int*   ei      = (const int*)d_in[26];
    const int*   batch   = (const int*)d_in[27];

    char* ws = (char*)d_ws;
    float*  w2r1   = (float*) (ws + OFF_W2R1);
    float*  w2r2   = (float*) (ws + OFF_W2R2);
    float*  msg1   = (float*) (ws + OFF_MSG1);
    float*  msg2   = (float*) (ws + OFF_MSG2);
    float4* ea_csr = (float4*)(ws + OFF_EACSR);
    int*    cnt    = (int*)   (ws + OFF_CNT);
    int*    deg    = (int*)   (ws + OFF_DEG);
    float*  psum   = (float*) (ws + OFF_PSUM);
    int*    done   = (int*)   (ws + OFF_DONE);
    float*  xmid   = (float*) (ws + OFF_XMID);
    int*    rowptr = (int*)   (ws + OFF_ROWPTR);
    int*    cursor = (int*)   (ws + OFF_CURSOR);
    int*    colptr = (int*)   (ws + OFF_COLPTR);
    int*    ccursor= (int*)   (ws + OFF_CCUR);
    int2*   meta   = (int2*)  (ws + OFF_META);

    hipMemsetAsync(ws + OFF_CNT, 0, 88256, stream);   // cnt+deg+psum+done

    k_pre<<<HBLK + WBLK, 256, 0, stream>>>(ei, cnt, deg,
                                           e1_w2, e1_b2, e2_w2, e2_b2, w2r1, w2r2);
    k_scan2<<<2, 1024, 0, stream>>>(deg, cnt, rowptr, cursor, colptr, ccursor);
    k_scatter<<<(EE + 255) / 256, 256, 0, stream>>>(ei, eattr,
                                                    cursor, ccursor, meta, ea_csr);

    k_f1<<<NBK, 256, 0, stream>>>(x, ea_csr, e1_w1, e1_b1, w2r1,
                                  meta, rowptr, msg1);
    k_mid<<<NBK, 256, 0, stream>>>(x, msg1, colptr, root1, bias1,
                                   bn1_g, bn1_b, bn1_m, bn1_v,
                                   ea_csr, e2_w1, e2_b1, w2r2,
                                   meta, rowptr, xmid, msg2);
    k_end<<<NBK, 256, 0, stream>>>(xmid, msg2, colptr, root2, bias2,
                                   bn2_g, bn2_b, bn2_m, bn2_v,
                                   batch, psum, done,
                                   r1_w, r1_b, r2_w, r2_b, (float*)d_out);
}